// Round 4
// baseline (296.000 us; speedup 1.0000x reference)
//
#include <hip/hip_runtime.h>

constexpr int D    = 128;   // node embedding dim
constexpr int K2   = 256;   // 2*D, layer-1 K
constexpr int H    = 256;   // hidden
constexpr int CLS  = 32;    // classes
constexpr int MT   = 64;    // edges per tile
constexpr int LSTR = 264;   // (fallback kernel only) padded LDS stride in ushort
constexpr int NBINS = 16384; // head-sort bins: bin = head>>3 (100k nodes -> 12500 bins)

typedef __attribute__((ext_vector_type(8))) __bf16 bf16x8;
typedef __attribute__((ext_vector_type(8))) unsigned short ushort8;
typedef __attribute__((ext_vector_type(4))) float f32x4;

static __device__ __forceinline__ unsigned short f2b(float f) {
  unsigned int u = __float_as_uint(f);
  u += 0x7FFFu + ((u >> 16) & 1u);   // RNE
  return (unsigned short)(u >> 16);
}

static __device__ __forceinline__ void gld_lds16(const unsigned short* gp, unsigned short* lp) {
  __builtin_amdgcn_global_load_lds(
      (const __attribute__((address_space(1))) void*)gp,
      (__attribute__((address_space(3))) void*)lp, 16, 0, 0);
}

// ---------------- prep kernels ------------------------------------------------
__global__ void prep_weights(const float* __restrict__ W1, const float* __restrict__ W2,
                             const void* __restrict__ eidx,
                             unsigned short* __restrict__ W1b, unsigned short* __restrict__ W2b,
                             unsigned short* __restrict__ W2s,
                             int* __restrict__ hist,
                             int* __restrict__ flag64) {
  int i = blockIdx.x * 256 + threadIdx.x;
  if (i < H * K2)  W1b[i] = f2b(W1[i]);
  if (hist && i < NBINS) hist[i] = 0;     // zero sort histogram (stream-ordered)
  if (i < CLS * H) {
    unsigned short v = f2b(W2[i]);
    W2b[i] = v;
    // pre-swizzled copy for LDS residency in the main kernel:
    // row r, data granule g (8 ushorts) -> slot (g&16)|((g^(r&15))&15)
    int r = i >> 8, e = i & 255, g = e >> 3, j = e & 7;
    int slot = (g & 16) | ((g ^ (r & 15)) & 15);
    W2s[r * 256 + slot * 8 + j] = v;
  }
  if (blockIdx.x == 0 && threadIdx.x == 0) {
    const unsigned int* p = (const unsigned int*)eidx;
    int is64 = 1;
    for (int j = 0; j < 64; ++j) if (p[2 * j + 1] != 0u) { is64 = 0; break; }
    *flag64 = is64;
  }
}

__global__ void prep_table(const float* __restrict__ emb, unsigned short* __restrict__ tab, int n8) {
  int i = blockIdx.x * 256 + threadIdx.x;
  if (i < n8) {
    const float* gp = emb + (size_t)i * 8;
    f32x4 lo = *(const f32x4*)gp, hi = *(const f32x4*)(gp + 4);
    ushort8 v;
    v[0] = f2b(lo[0]); v[1] = f2b(lo[1]); v[2] = f2b(lo[2]); v[3] = f2b(lo[3]);
    v[4] = f2b(hi[0]); v[5] = f2b(hi[1]); v[6] = f2b(hi[2]); v[7] = f2b(hi[3]);
    *(ushort8*)(tab + (size_t)i * 8) = v;
  }
}

// convert edge indices to i32 AND (optionally) histogram head nodes
__global__ void prep_idx_hist(const void* __restrict__ eidx, int* __restrict__ idx32,
                              int* __restrict__ hist, int E) {
  __shared__ int sflag;
  if (threadIdx.x == 0) {
    const unsigned int* p = (const unsigned int*)eidx;
    int is64 = 1;
    for (int j = 0; j < 64; ++j) if (p[2 * j + 1] != 0u) { is64 = 0; break; }
    sflag = is64;
  }
  __syncthreads();
  int j = blockIdx.x * 256 + threadIdx.x;
  if (j < 2 * E) {
    int v = sflag ? (int)((const long long*)eidx)[j] : ((const int*)eidx)[j];
    idx32[j] = v;
    if (hist && j < E) atomicAdd(&hist[min(v >> 3, NBINS - 1)], 1);
  }
}

// exclusive scan of hist[NBINS] -> offs[NBINS]; single 1024-thread block
__global__ __launch_bounds__(1024)
void scan_bins(const int* __restrict__ hist, int* __restrict__ offs) {
  __shared__ int ps[1024];
  const int tIdx = threadIdx.x;
  const int b0 = tIdx * (NBINS / 1024);
  int s = 0;
  #pragma unroll
  for (int i = 0; i < NBINS / 1024; ++i) s += hist[b0 + i];
  ps[tIdx] = s;
  __syncthreads();
  for (int off = 1; off < 1024; off <<= 1) {
    int v = (tIdx >= off) ? ps[tIdx - off] : 0;
    __syncthreads();
    ps[tIdx] += v;
    __syncthreads();
  }
  int run = ps[tIdx] - s;   // exclusive prefix of this thread's chunk
  #pragma unroll
  for (int i = 0; i < NBINS / 1024; ++i) { int h = hist[b0 + i]; offs[b0 + i] = run; run += h; }
}

// scatter edges into head-sorted order; perm maps sorted pos -> original edge
__global__ void scatter_edges(const int* __restrict__ idx32, int* __restrict__ offs,
                              int* __restrict__ sidx, int* __restrict__ perm, int E) {
  int j = blockIdx.x * 256 + threadIdx.x;
  if (j < E) {
    int h = idx32[j];
    int pos = atomicAdd(&offs[min(h >> 3, NBINS - 1)], 1);
    sidx[pos]     = h;
    sidx[E + pos] = idx32[E + j];
    perm[pos]     = j;
  }
}

// ---------------- main fused kernel (v5) --------------------------------------
// v3 structure (proven 120us: 256 thr, counted vmcnt, W2 in LDS, NT stores)
// + head-sorted edges: tiles walk the node table near-sequentially with ~5x
//   head duplication adjacency -> head gathers hit L1/L2 instead of fabric.
// + contiguous per-block tile chunks, XCD-affine (cid=(b&7)*(nbk/8)+b/8):
//   each XCD's head working set = its ~3.2MB slice of tab -> L2-resident.
// + out stores scattered via perm (loaded FIRST each iter so its waitcnt is
//   vmcnt(8), never draining the in-flight stage gathers).
__global__ __launch_bounds__(256, 2)
void edge_mlp5(const unsigned short* __restrict__ tab, const int* __restrict__ sidx,
               const int* __restrict__ perm,
               const unsigned short* __restrict__ W1b, const unsigned short* __restrict__ W2s,
               const float* __restrict__ b1, const float* __restrict__ b2,
               float* __restrict__ out, int E, int ntiles) {
  __shared__ unsigned short Xs[2][MT * 256];   // 2 x 32 KB
  __shared__ unsigned short W2l[CLS * 256];    // 16 KB, swizzled

  const int tid  = threadIdx.x;
  const int lane = tid & 63;
  const int w    = tid >> 6;
  const int l16  = lane & 15;
  const int q    = lane >> 4;

  // Persistent W1 A-fragments: hidden row 64w+16a+l16, k = 32kk+8q..+8
  bf16x8 afr[4][8];
  #pragma unroll
  for (int a = 0; a < 4; ++a) {
    const unsigned short* rp = W1b + (64 * w + 16 * a + l16) * K2 + q * 8;
    #pragma unroll
    for (int kk = 0; kk < 8; ++kk)
      afr[a][kk] = *(const bf16x8*)(rp + kk * 32);
  }
  f32x4 binit[4];
  #pragma unroll
  for (int a = 0; a < 4; ++a) binit[a] = *(const f32x4*)(b1 + 64 * w + 16 * a + 4 * q);
  f32x4 b2init[2];
  #pragma unroll
  for (int ct = 0; ct < 2; ++ct) b2init[ct] = *(const f32x4*)(b2 + 16 * ct + 4 * q);

  // Stage swizzled W2 into LDS once (linear copy; swizzle was applied in prep).
  #pragma unroll
  for (int c = 0; c < 4; ++c) {
    const unsigned short* gp = W2s + (c * 256 + 64 * w + lane) * 8;
    unsigned short* lp = &W2l[(c * 256 + 64 * w) * 8];   // wave-uniform base
    gld_lds16(gp, lp);
  }

  // staging geometry (per wave: its 16 edges, 8 instrs x 2 edges x 1KB LDS)
  const int G    = lane & 31;        // LDS slot granule within row
  const int half = G >> 4;           // 0 = head node, 1 = tail node
  const int sub  = lane >> 5;        // which of the 2 edges in this instr

  auto stage = [&](int t, int b) {
    #pragma unroll
    for (int c = 0; c < 8; ++c) {
      int mrow = 16 * w + 2 * c + sub;
      int e = t * MT + mrow; if (e >= E) e = E - 1;
      int id = sidx[half ? (E + e) : e];
      const unsigned short* gp = tab + (size_t)id * D + ((G ^ mrow) & 15) * 8;
      unsigned short* lp = &Xs[b][(16 * w + 2 * c) * 256];   // wave-uniform base
      gld_lds16(gp, lp);
    }
  };

  // contiguous chunk of tiles, XCD-affine (see header comment)
  const int nbk  = gridDim.x;                      // multiple of 8
  const int cid  = (blockIdx.x & 7) * (nbk >> 3) + (blockIdx.x >> 3);
  const int base = ntiles / nbk, ext = ntiles % nbk;
  const int tstart = cid * base + min(cid, ext);
  const int tend   = tstart + base + (cid < ext ? 1 : 0);

  int buf = 0;
  if (tstart < tend) stage(tstart, 0);
  // prologue: everything (W2l + first X tile) must land before first read
  asm volatile("s_waitcnt vmcnt(0)\n\ts_barrier" ::: "memory");

  const int mrow_st = 16 * w + l16;               // this lane's store row
  for (int t = tstart; t < tend; ++t) {
    // perm for the CURRENT tile, loaded before stage(tn) so the compiler's
    // wait for it never drains the gather queue.
    int e_s = t * MT + mrow_st;
    int pe = 0;
    if (e_s < E) pe = perm[e_s];

    int tn = t + 1;
    if (tn < tend) stage(tn, buf ^ 1);       // fire-and-forget into other buffer
    __builtin_amdgcn_sched_barrier(0);       // pin: stage glds stay oldest in vmcnt queue

    // ---- layer 1 ----
    f32x4 acc[4][4];
    #pragma unroll
    for (int a = 0; a < 4; ++a)
      #pragma unroll
      for (int tt = 0; tt < 4; ++tt) acc[a][tt] = binit[a];

    __builtin_amdgcn_s_setprio(1);
    #pragma unroll
    for (int tt = 0; tt < 4; ++tt) {
      const unsigned short* rowp = &Xs[buf][(16 * tt + l16) * 256];
      #pragma unroll
      for (int kk = 0; kk < 8; ++kk) {
        int slot = (4 * kk + q) ^ l16;               // swizzled slot (bit4 preserved)
        bf16x8 bfrag = *(const bf16x8*)(rowp + slot * 8);
        #pragma unroll
        for (int a = 0; a < 4; ++a)
          acc[a][tt] = __builtin_amdgcn_mfma_f32_16x16x32_bf16(afr[a][kk], bfrag, acc[a][tt], 0, 0, 0);
      }
    }
    __builtin_amdgcn_s_setprio(0);
    // B2: WAR barrier only; NO vmcnt drain (stage gathers stay in flight).
    asm volatile("s_barrier" ::: "memory");

    // ---- ReLU + bf16 -> Y[m][n] in Xs[buf] (swizzled) ----
    #pragma unroll
    for (int a = 0; a < 4; ++a) {
      int dg   = 8 * w + 2 * a + (q >> 1);           // data granule of this lane's 8B
      int qodd = (q & 1) * 4;                        // ushort offset within granule
      #pragma unroll
      for (int tt = 0; tt < 4; ++tt) {
        int m = 16 * tt + l16;
        f32x4 v = acc[a][tt];
        unsigned int p0 = (unsigned int)f2b(fmaxf(v[0], 0.f)) | ((unsigned int)f2b(fmaxf(v[1], 0.f)) << 16);
        unsigned int p1 = (unsigned int)f2b(fmaxf(v[2], 0.f)) | ((unsigned int)f2b(fmaxf(v[3], 0.f)) << 16);
        int slot = (dg & 16) | ((dg ^ l16) & 15);
        uint2 pp; pp.x = p0; pp.y = p1;
        *(uint2*)(&Xs[buf][m * 256 + slot * 8 + qodd]) = pp;
      }
    }
    // B3: Y writes visible to all waves; still no vmcnt drain.
    asm volatile("s_waitcnt lgkmcnt(0)\n\ts_barrier" ::: "memory");

    // ---- layer 2: wave w -> sorted edges [16w,16w+16), all 32 classes ----
    f32x4 acc2[2];
    acc2[0] = b2init[0]; acc2[1] = b2init[1];
    const unsigned short* yrow = &Xs[buf][mrow_st * 256];
    #pragma unroll
    for (int kk = 0; kk < 8; ++kk) {
      int slot = (4 * kk + q) ^ l16;
      bf16x8 yfrag = *(const bf16x8*)(yrow + slot * 8);
      #pragma unroll
      for (int ct = 0; ct < 2; ++ct) {
        bf16x8 wf = *(const bf16x8*)(&W2l[(16 * ct + l16) * 256 + slot * 8]);
        acc2[ct] = __builtin_amdgcn_mfma_f32_16x16x32_bf16(wf, yfrag, acc2[ct], 0, 0, 0);
      }
    }
    if (e_s < E) {
      #pragma unroll
      for (int ct = 0; ct < 2; ++ct)
        __builtin_nontemporal_store(acc2[ct], (f32x4*)(out + (size_t)pe * CLS + 16 * ct + 4 * q));
    }
    // drain the 8 stage glds (oldest); the 2 newest vmem ops are the out
    // stores -> vmcnt(2) skips waiting for their acks.
    asm volatile("s_waitcnt vmcnt(2)\n\ts_barrier" ::: "memory");
    buf ^= 1;
  }
}

// ---------------- v3 fallback (ws fits table+idx but not sort arrays) ---------
__global__ __launch_bounds__(256, 2)
void edge_mlp3(const unsigned short* __restrict__ tab, const int* __restrict__ idx32,
               const unsigned short* __restrict__ W1b, const unsigned short* __restrict__ W2s,
               const float* __restrict__ b1, const float* __restrict__ b2,
               float* __restrict__ out, int E, int ntiles) {
  __shared__ unsigned short Xs[2][MT * 256];
  __shared__ unsigned short W2l[CLS * 256];

  const int tid  = threadIdx.x;
  const int lane = tid & 63;
  const int w    = tid >> 6;
  const int l16  = lane & 15;
  const int q    = lane >> 4;

  bf16x8 afr[4][8];
  #pragma unroll
  for (int a = 0; a < 4; ++a) {
    const unsigned short* rp = W1b + (64 * w + 16 * a + l16) * K2 + q * 8;
    #pragma unroll
    for (int kk = 0; kk < 8; ++kk)
      afr[a][kk] = *(const bf16x8*)(rp + kk * 32);
  }
  f32x4 binit[4];
  #pragma unroll
  for (int a = 0; a < 4; ++a) binit[a] = *(const f32x4*)(b1 + 64 * w + 16 * a + 4 * q);
  f32x4 b2init[2];
  #pragma unroll
  for (int ct = 0; ct < 2; ++ct) b2init[ct] = *(const f32x4*)(b2 + 16 * ct + 4 * q);

  #pragma unroll
  for (int c = 0; c < 4; ++c) {
    const unsigned short* gp = W2s + (c * 256 + 64 * w + lane) * 8;
    unsigned short* lp = &W2l[(c * 256 + 64 * w) * 8];
    gld_lds16(gp, lp);
  }

  const int G    = lane & 31;
  const int half = G >> 4;
  const int sub  = lane >> 5;

  auto stage = [&](int t, int b) {
    #pragma unroll
    for (int c = 0; c < 8; ++c) {
      int mrow = 16 * w + 2 * c + sub;
      int e = t * MT + mrow; if (e >= E) e = E - 1;
      int id = idx32[half ? (E + e) : e];
      const unsigned short* gp = tab + (size_t)id * D + ((G ^ mrow) & 15) * 8;
      unsigned short* lp = &Xs[b][(16 * w + 2 * c) * 256];
      gld_lds16(gp, lp);
    }
  };

  int buf = 0;
  int t0 = blockIdx.x;
  if (t0 < ntiles) stage(t0, 0);
  asm volatile("s_waitcnt vmcnt(0)\n\ts_barrier" ::: "memory");

  for (int t = t0; t < ntiles; t += gridDim.x) {
    int tn = t + gridDim.x;
    if (tn < ntiles) stage(tn, buf ^ 1);
    __builtin_amdgcn_sched_barrier(0);

    f32x4 acc[4][4];
    #pragma unroll
    for (int a = 0; a < 4; ++a)
      #pragma unroll
      for (int tt = 0; tt < 4; ++tt) acc[a][tt] = binit[a];

    __builtin_amdgcn_s_setprio(1);
    #pragma unroll
    for (int tt = 0; tt < 4; ++tt) {
      const unsigned short* rowp = &Xs[buf][(16 * tt + l16) * 256];
      #pragma unroll
      for (int kk = 0; kk < 8; ++kk) {
        int slot = (4 * kk + q) ^ l16;
        bf16x8 bfrag = *(const bf16x8*)(rowp + slot * 8);
        #pragma unroll
        for (int a = 0; a < 4; ++a)
          acc[a][tt] = __builtin_amdgcn_mfma_f32_16x16x32_bf16(afr[a][kk], bfrag, acc[a][tt], 0, 0, 0);
      }
    }
    __builtin_amdgcn_s_setprio(0);
    asm volatile("s_barrier" ::: "memory");

    #pragma unroll
    for (int a = 0; a < 4; ++a) {
      int dg   = 8 * w + 2 * a + (q >> 1);
      int qodd = (q & 1) * 4;
      #pragma unroll
      for (int tt = 0; tt < 4; ++tt) {
        int m = 16 * tt + l16;
        f32x4 v = acc[a][tt];
        unsigned int p0 = (unsigned int)f2b(fmaxf(v[0], 0.f)) | ((unsigned int)f2b(fmaxf(v[1], 0.f)) << 16);
        unsigned int p1 = (unsigned int)f2b(fmaxf(v[2], 0.f)) | ((unsigned int)f2b(fmaxf(v[3], 0.f)) << 16);
        int slot = (dg & 16) | ((dg ^ l16) & 15);
        uint2 pp; pp.x = p0; pp.y = p1;
        *(uint2*)(&Xs[buf][m * 256 + slot * 8 + qodd]) = pp;
      }
    }
    asm volatile("s_waitcnt lgkmcnt(0)\n\ts_barrier" ::: "memory");

    f32x4 acc2[2];
    acc2[0] = b2init[0]; acc2[1] = b2init[1];
    const int mrow = 16 * w + l16;
    const unsigned short* yrow = &Xs[buf][mrow * 256];
    #pragma unroll
    for (int kk = 0; kk < 8; ++kk) {
      int slot = (4 * kk + q) ^ l16;
      bf16x8 yfrag = *(const bf16x8*)(yrow + slot * 8);
      #pragma unroll
      for (int ct = 0; ct < 2; ++ct) {
        bf16x8 wf = *(const bf16x8*)(&W2l[(16 * ct + l16) * 256 + slot * 8]);
        acc2[ct] = __builtin_amdgcn_mfma_f32_16x16x32_bf16(wf, yfrag, acc2[ct], 0, 0, 0);
      }
    }
    int e = t * MT + mrow;
    if (e < E) {
      #pragma unroll
      for (int ct = 0; ct < 2; ++ct)
        __builtin_nontemporal_store(acc2[ct], (f32x4*)(out + (size_t)e * CLS + 16 * ct + 4 * q));
    }
    asm volatile("s_waitcnt vmcnt(2)\n\ts_barrier" ::: "memory");
    buf ^= 1;
  }
}

// ---------------- fallback v1 (ws fits weights only) --------------------------
__global__ __launch_bounds__(256, 2)
void edge_mlp_v1(const float* __restrict__ emb, const void* __restrict__ eidx,
                 const unsigned short* __restrict__ W1b, const unsigned short* __restrict__ W2b,
                 const float* __restrict__ b1, const float* __restrict__ b2,
                 const int* __restrict__ flag64,
                 float* __restrict__ out, int E, int ntiles) {
  __shared__ unsigned short Xsp[MT * LSTR];
  const int tid  = threadIdx.x;
  const int lane = tid & 63;
  const int w    = tid >> 6;
  const int l16  = lane & 15;
  const int q    = lane >> 4;
  const int is64 = *flag64;

  bf16x8 afr[4][8];
  #pragma unroll
  for (int a = 0; a < 4; ++a) {
    const unsigned short* rp = W1b + (64 * w + 16 * a + l16) * K2 + q * 8;
    #pragma unroll
    for (int kk = 0; kk < 8; ++kk) afr[a][kk] = *(const bf16x8*)(rp + kk * 32);
  }
  f32x4 binit[4];
  #pragma unroll
  for (int a = 0; a < 4; ++a) binit[a] = *(const f32x4*)(b1 + 64 * w + 16 * a + 4 * q);
  f32x4 b2init[2];
  #pragma unroll
  for (int ct = 0; ct < 2; ++ct) b2init[ct] = *(const f32x4*)(b2 + 16 * ct + 4 * q);

  for (int t = blockIdx.x; t < ntiles; t += gridDim.x) {
    const int e0 = t * MT;
    #pragma unroll
    for (int c = 0; c < 8; ++c) {
      int chunk = tid + c * 256;
      int m = chunk >> 5, col8 = chunk & 31;
      int e = e0 + m; if (e >= E) e = E - 1;
      int iofs = (col8 < 16) ? e : (E + e);
      long long node = is64 ? ((const long long*)eidx)[iofs] : (long long)(((const int*)eidx)[iofs]);
      const float* gp = emb + (int)node * D + (col8 & 15) * 8;
      f32x4 lo = *(const f32x4*)gp, hi = *(const f32x4*)(gp + 4);
      ushort8 v;
      v[0] = f2b(lo[0]); v[1] = f2b(lo[1]); v[2] = f2b(lo[2]); v[3] = f2b(lo[3]);
      v[4] = f2b(hi[0]); v[5] = f2b(hi[1]); v[6] = f2b(hi[2]); v[7] = f2b(hi[3]);
      *(ushort8*)&Xsp[m * LSTR + col8 * 8] = v;
    }
    __syncthreads();
    f32x4 acc[4][4];
    #pragma unroll
    for (int a = 0; a < 4; ++a)
      #pragma unroll
      for (int tt = 0; tt < 4; ++tt) acc[a][tt] = binit[a];
    #pragma unroll
    for (int tt = 0; tt < 4; ++tt) {
      #pragma unroll
      for (int kk = 0; kk < 8; ++kk) {
        bf16x8 bfrag = *(const bf16x8*)&Xsp[(16 * tt + l16) * LSTR + kk * 32 + q * 8];
        #pragma unroll
        for (int a = 0; a < 4; ++a)
          acc[a][tt] = __builtin_amdgcn_mfma_f32_16x16x32_bf16(afr[a][kk], bfrag, acc[a][tt], 0, 0, 0);
      }
    }
    __syncthreads();
    #pragma unroll
    for (int a = 0; a < 4; ++a) {
      int n0 = 64 * w + 16 * a + 4 * q;
      #pragma unroll
      for (int tt = 0; tt < 4; ++tt) {
        f32x4 v = acc[a][tt];
        unsigned int p0 = (unsigned int)f2b(fmaxf(v[0], 0.f)) | ((unsigned int)f2b(fmaxf(v[1], 0.f)) << 16);
        unsigned int p1 = (unsigned int)f2b(fmaxf(v[2], 0.f)) | ((unsigned int)f2b(fmaxf(v[3], 0.f)) << 16);
        uint2 pp; pp.x = p0; pp.y = p1;
        *(uint2*)&Xsp[(16 * tt + l16) * LSTR + n0] = pp;
      }
    }
    __syncthreads();
    f32x4 acc2[2];
    acc2[0] = b2init[0]; acc2[1] = b2init[1];
    const int mrow = 16 * w + l16;
    #pragma unroll
    for (int kk = 0; kk < 8; ++kk) {
      bf16x8 yfrag = *(const bf16x8*)&Xsp[mrow * LSTR + kk * 32 + q * 8];
      #pragma unroll
      for (int ct = 0; ct < 2; ++ct) {
        bf16x8 wf = *(const bf16x8*)(W2b + (16 * ct + l16) * H + kk * 32 + q * 8);
        acc2[ct] = __builtin_amdgcn_mfma_f32_16x16x32_bf16(wf, yfrag, acc2[ct], 0, 0, 0);
      }
    }
    int e = e0 + mrow;
    if (e < E) {
      #pragma unroll
      for (int ct = 0; ct < 2; ++ct)
        *(f32x4*)(out + (size_t)e * CLS + 16 * ct + 4 * q) = acc2[ct];
    }
    __syncthreads();
  }
}

// ---------------- last-resort naive ------------------------------------------
__global__ void edge_mlp_naive(const float* __restrict__ emb, const void* __restrict__ eidx,
                               const float* __restrict__ W1, const float* __restrict__ b1,
                               const float* __restrict__ W2, const float* __restrict__ b2,
                               float* __restrict__ out, int E) {
  __shared__ float x[K2];
  __shared__ float y[H];
  __shared__ int flag;
  int e = blockIdx.x;
  if (threadIdx.x == 0) {
    const unsigned int* p = (const unsigned int*)eidx;
    int is64 = 1;
    for (int j = 0; j < 16; ++j) if (p[2 * j + 1] != 0u) { is64 = 0; break; }
    flag = is64;
  }
  __syncthreads();
  int tid = threadIdx.x;
  long long s, d;
  if (flag) { s = ((const long long*)eidx)[e]; d = ((const long long*)eidx)[E + e]; }
  else      { s = ((const int*)eidx)[e];       d = ((const int*)eidx)[E + e]; }
  if (tid < D) { x[tid] = emb[(int)s * D + tid]; x[D + tid] = emb[(int)d * D + tid]; }
  __syncthreads();
  float acc = b1[tid];
  const float* wr = W1 + tid * K2;
  for (int k = 0; k < K2; ++k) acc += x[k] * wr[k];
  y[tid] = fmaxf(acc, 0.f);
  __syncthreads();
  if (tid < CLS) {
    float a2 = b2[tid];
    const float* w2 = W2 + tid * H;
    for (int k = 0; k < H; ++k) a2 += y[k] * w2[k];
    out[(size_t)e * CLS + tid] = a2;
  }
}

extern "C" void kernel_launch(void* const* d_in, const int* in_sizes, int n_in,
                              void* d_out, int out_size, void* d_ws, size_t ws_size,
                              hipStream_t stream) {
  const float* emb  = (const float*)d_in[0];
  const void*  eidx = d_in[1];
  const float* W1   = (const float*)d_in[2];
  const float* b1   = (const float*)d_in[3];
  const float* W2   = (const float*)d_in[4];
  const float* b2   = (const float*)d_in[5];
  float* out = (float*)d_out;
  const int nodes_elems = in_sizes[0];   // N_NODES * D
  const int E = in_sizes[1] / 2;
  const int ntiles = (E + MT - 1) / MT;

  // ws layout: [tab][W1b][W2b][W2s][idx32 2E][sidx 2E][perm E][hist][offs][flag]
  size_t off_tab  = 0;
  size_t off_w1   = (off_tab + (size_t)nodes_elems * 2 + 15) & ~(size_t)15;
  size_t off_w2   = off_w1 + (size_t)H * K2 * 2;
  size_t off_w2s  = off_w2 + (size_t)CLS * H * 2;
  size_t off_idx  = (off_w2s + (size_t)CLS * H * 2 + 15) & ~(size_t)15;
  size_t off_sidx = off_idx + (size_t)2 * E * 4;
  size_t off_perm = off_sidx + (size_t)2 * E * 4;
  size_t off_hist = off_perm + (size_t)E * 4;
  size_t off_offs = off_hist + (size_t)NBINS * 4;
  size_t off_flag = off_offs + (size_t)NBINS * 4;
  size_t need_sort    = off_flag + 16;
  size_t need_v3      = off_sidx + 16;   // through idx32 + flag
  size_t need_weights = (size_t)(H * K2 + CLS * H) * 2 + 64;

  if (ws_size >= need_sort) {
    unsigned short* tab   = (unsigned short*)((char*)d_ws + off_tab);
    unsigned short* W1b   = (unsigned short*)((char*)d_ws + off_w1);
    unsigned short* W2b   = (unsigned short*)((char*)d_ws + off_w2);
    unsigned short* W2s   = (unsigned short*)((char*)d_ws + off_w2s);
    int*            idx32 = (int*)((char*)d_ws + off_idx);
    int*            sidx  = (int*)((char*)d_ws + off_sidx);
    int*            perm  = (int*)((char*)d_ws + off_perm);
    int*            hist  = (int*)((char*)d_ws + off_hist);
    int*            offs  = (int*)((char*)d_ws + off_offs);
    int*            flag  = (int*)((char*)d_ws + off_flag);

    prep_weights<<<(H * K2 + 255) / 256, 256, 0, stream>>>(W1, W2, eidx, W1b, W2b, W2s, hist, flag);
    prep_table<<<(nodes_elems / 8 + 255) / 256, 256, 0, stream>>>(emb, tab, nodes_elems / 8);
    prep_idx_hist<<<(2 * E + 255) / 256, 256, 0, stream>>>(eidx, idx32, hist, E);
    scan_bins<<<1, 1024, 0, stream>>>(hist, offs);
    scatter_edges<<<(E + 255) / 256, 256, 0, stream>>>(idx32, offs, sidx, perm, E);
    edge_mlp5<<<512, 256, 0, stream>>>(tab, sidx, perm, W1b, W2s, b1, b2, out, E, ntiles);
  } else if (ws_size >= need_v3) {
    unsigned short* tab   = (unsigned short*)((char*)d_ws + off_tab);
    unsigned short* W1b   = (unsigned short*)((char*)d_ws + off_w1);
    unsigned short* W2b   = (unsigned short*)((char*)d_ws + off_w2);
    unsigned short* W2s   = (unsigned short*)((char*)d_ws + off_w2s);
    int*            idx32 = (int*)((char*)d_ws + off_idx);
    int*            flag  = (int*)((char*)d_ws + off_sidx);
    prep_weights<<<(H * K2 + 255) / 256, 256, 0, stream>>>(W1, W2, eidx, W1b, W2b, W2s, (int*)0, flag);
    prep_table<<<(nodes_elems / 8 + 255) / 256, 256, 0, stream>>>(emb, tab, nodes_elems / 8);
    prep_idx_hist<<<(2 * E + 255) / 256, 256, 0, stream>>>(eidx, idx32, (int*)0, E);
    edge_mlp3<<<512, 256, 0, stream>>>(tab, idx32, W1b, W2s, b1, b2, out, E, ntiles);
  } else if (ws_size >= need_weights) {
    unsigned short* W1b = (unsigned short*)d_ws;
    unsigned short* W2b = W1b + H * K2;
    int* flag = (int*)(W2b + CLS * H);
    prep_weights<<<(H * K2 + 255) / 256, 256, 0, stream>>>(W1, W2, eidx, W1b, W2b, W2b, (int*)0, flag);
    edge_mlp_v1<<<1024, 256, 0, stream>>>(emb, eidx, W1b, W2b, b1, b2, flag, out, E, ntiles);
  } else {
    edge_mlp_naive<<<E, H, 0, stream>>>(emb, eidx, W1, b1, W2, b2, out, E);
  }
}

// Round 5
// 215.291 us; speedup vs baseline: 1.3749x; 1.3749x over previous
//
#include <hip/hip_runtime.h>

constexpr int D    = 128;   // node embedding dim
constexpr int K2   = 256;   // 2*D, layer-1 K
constexpr int H    = 256;   // hidden
constexpr int CLS  = 32;    // classes
constexpr int MT   = 64;    // edges per tile
constexpr int LSTR = 264;   // (fallback kernel only) padded LDS stride in ushort

typedef __attribute__((ext_vector_type(8))) __bf16 bf16x8;
typedef __attribute__((ext_vector_type(8))) unsigned short ushort8;
typedef __attribute__((ext_vector_type(4))) float f32x4;

static __device__ __forceinline__ unsigned short f2b(float f) {
  unsigned int u = __float_as_uint(f);
  u += 0x7FFFu + ((u >> 16) & 1u);   // RNE
  return (unsigned short)(u >> 16);
}

static __device__ __forceinline__ void gld_lds16(const unsigned short* gp, unsigned short* lp) {
  __builtin_amdgcn_global_load_lds(
      (const __attribute__((address_space(1))) void*)gp,
      (__attribute__((address_space(3))) void*)lp, 16, 0, 0);
}

// ---------------- fused prep (ONE launch) -------------------------------------
// Launch-overhead is ~26 us/launch on this harness (measured R0-R4), so all
// prep work shares one grid: thread i does
//   i < n8      : bf16 node-table granule i (the bulk, 1.6M granules)
//   i < H*K2    : W1 bf16 convert
//   i < CLS*H   : W2 bf16 convert + swizzled copy for LDS residency
//   i < 2E      : edge index widen to i32 (per-block is64 re-detection)
__global__ void prep_all(const float* __restrict__ emb, const void* __restrict__ eidx,
                         const float* __restrict__ W1, const float* __restrict__ W2,
                         unsigned short* __restrict__ tab,
                         unsigned short* __restrict__ W1b,
                         unsigned short* __restrict__ W2b,
                         unsigned short* __restrict__ W2s,
                         int* __restrict__ idx32, int n8, int E2) {
  __shared__ int sflag;
  if (threadIdx.x == 0) {
    const unsigned int* p = (const unsigned int*)eidx;
    int is64 = 1;
    for (int j = 0; j < 64; ++j) if (p[2 * j + 1] != 0u) { is64 = 0; break; }
    sflag = is64;
  }
  __syncthreads();
  int i = blockIdx.x * 256 + threadIdx.x;
  if (i < n8) {
    const float* gp = emb + (size_t)i * 8;
    f32x4 lo = *(const f32x4*)gp, hi = *(const f32x4*)(gp + 4);
    ushort8 v;
    v[0] = f2b(lo[0]); v[1] = f2b(lo[1]); v[2] = f2b(lo[2]); v[3] = f2b(lo[3]);
    v[4] = f2b(hi[0]); v[5] = f2b(hi[1]); v[6] = f2b(hi[2]); v[7] = f2b(hi[3]);
    *(ushort8*)(tab + (size_t)i * 8) = v;
  }
  if (i < H * K2) W1b[i] = f2b(W1[i]);
  if (i < CLS * H) {
    unsigned short v = f2b(W2[i]);
    W2b[i] = v;
    // row r, data granule g (8 ushorts) -> slot (g&16)|((g^(r&15))&15)
    int r = i >> 8, e = i & 255, g = e >> 3, j = e & 7;
    int slot = (g & 16) | ((g ^ (r & 15)) & 15);
    W2s[r * 256 + slot * 8 + j] = v;
  }
  if (i < E2)
    idx32[i] = sflag ? (int)((const long long*)eidx)[i] : ((const int*)eidx)[i];
}

// ---------------- legacy prep (fallback paths only) ---------------------------
__global__ void prep_weights(const float* __restrict__ W1, const float* __restrict__ W2,
                             const void* __restrict__ eidx,
                             unsigned short* __restrict__ W1b, unsigned short* __restrict__ W2b,
                             int* __restrict__ flag64) {
  int i = blockIdx.x * 256 + threadIdx.x;
  if (i < H * K2)  W1b[i] = f2b(W1[i]);
  if (i < CLS * H) W2b[i] = f2b(W2[i]);
  if (blockIdx.x == 0 && threadIdx.x == 0) {
    const unsigned int* p = (const unsigned int*)eidx;
    int is64 = 1;
    for (int j = 0; j < 64; ++j) if (p[2 * j + 1] != 0u) { is64 = 0; break; }
    *flag64 = is64;
  }
}

// ---------------- main fused kernel (v3, proven 120 us) -----------------------
// 4 waves, 64 edges/tile, double-buffered X staging via global_load_lds(16B)
// from the bf16 node table; counted-waitcnt barriers (gathers never drained
// mid-tile); W2 LDS-resident; NT out stores; persistent 512-block grid.
__global__ __launch_bounds__(256, 2)
void edge_mlp3(const unsigned short* __restrict__ tab, const int* __restrict__ idx32,
               const unsigned short* __restrict__ W1b, const unsigned short* __restrict__ W2s,
               const float* __restrict__ b1, const float* __restrict__ b2,
               float* __restrict__ out, int E, int ntiles) {
  __shared__ unsigned short Xs[2][MT * 256];   // 2 x 32 KB
  __shared__ unsigned short W2l[CLS * 256];    // 16 KB, swizzled

  const int tid  = threadIdx.x;
  const int lane = tid & 63;
  const int w    = tid >> 6;
  const int l16  = lane & 15;
  const int q    = lane >> 4;

  // Persistent W1 A-fragments: hidden row 64w+16a+l16, k = 32kk+8q..+8
  bf16x8 afr[4][8];
  #pragma unroll
  for (int a = 0; a < 4; ++a) {
    const unsigned short* rp = W1b + (64 * w + 16 * a + l16) * K2 + q * 8;
    #pragma unroll
    for (int kk = 0; kk < 8; ++kk)
      afr[a][kk] = *(const bf16x8*)(rp + kk * 32);
  }
  f32x4 binit[4];
  #pragma unroll
  for (int a = 0; a < 4; ++a) binit[a] = *(const f32x4*)(b1 + 64 * w + 16 * a + 4 * q);
  f32x4 b2init[2];
  #pragma unroll
  for (int ct = 0; ct < 2; ++ct) b2init[ct] = *(const f32x4*)(b2 + 16 * ct + 4 * q);

  // Stage swizzled W2 into LDS once (linear copy; swizzle was applied in prep).
  #pragma unroll
  for (int c = 0; c < 4; ++c) {
    const unsigned short* gp = W2s + (c * 256 + 64 * w + lane) * 8;
    unsigned short* lp = &W2l[(c * 256 + 64 * w) * 8];   // wave-uniform base
    gld_lds16(gp, lp);
  }

  // staging geometry (per wave: its 16 edges, 8 instrs x 2 edges x 1KB LDS)
  const int G    = lane & 31;        // LDS slot granule within row
  const int half = G >> 4;           // 0 = head node, 1 = tail node
  const int sub  = lane >> 5;        // which of the 2 edges in this instr

  auto stage = [&](int t, int b) {
    #pragma unroll
    for (int c = 0; c < 8; ++c) {
      int mrow = 16 * w + 2 * c + sub;
      int e = t * MT + mrow; if (e >= E) e = E - 1;
      int id = idx32[half ? (E + e) : e];
      const unsigned short* gp = tab + (size_t)id * D + ((G ^ mrow) & 15) * 8;
      unsigned short* lp = &Xs[b][(16 * w + 2 * c) * 256];   // wave-uniform base
      gld_lds16(gp, lp);
    }
  };

  int buf = 0;
  int t0 = blockIdx.x;
  if (t0 < ntiles) stage(t0, 0);
  // prologue: everything (W2l + first X tile) must land before first read
  asm volatile("s_waitcnt vmcnt(0)\n\ts_barrier" ::: "memory");

  for (int t = t0; t < ntiles; t += gridDim.x) {
    int tn = t + gridDim.x;
    if (tn < ntiles) stage(tn, buf ^ 1);     // fire-and-forget into other buffer
    __builtin_amdgcn_sched_barrier(0);       // pin: stage glds stay oldest in vmcnt queue

    // ---- layer 1 ----
    f32x4 acc[4][4];
    #pragma unroll
    for (int a = 0; a < 4; ++a)
      #pragma unroll
      for (int tt = 0; tt < 4; ++tt) acc[a][tt] = binit[a];

    __builtin_amdgcn_s_setprio(1);
    #pragma unroll
    for (int tt = 0; tt < 4; ++tt) {
      const unsigned short* rowp = &Xs[buf][(16 * tt + l16) * 256];
      #pragma unroll
      for (int kk = 0; kk < 8; ++kk) {
        int slot = (4 * kk + q) ^ l16;               // swizzled slot (bit4 preserved)
        bf16x8 bfrag = *(const bf16x8*)(rowp + slot * 8);
        #pragma unroll
        for (int a = 0; a < 4; ++a)
          acc[a][tt] = __builtin_amdgcn_mfma_f32_16x16x32_bf16(afr[a][kk], bfrag, acc[a][tt], 0, 0, 0);
      }
    }
    __builtin_amdgcn_s_setprio(0);
    // B2: WAR barrier only. Layer-1 ds_reads were all consumed by MFMAs above
    // (issued pre-barrier; LDS pipe order protects). Crucially: NO vmcnt drain,
    // so stage(tn) gathers stay in flight.
    asm volatile("s_barrier" ::: "memory");

    // ---- ReLU + bf16 -> Y[m][n] in Xs[buf] (swizzled) ----
    #pragma unroll
    for (int a = 0; a < 4; ++a) {
      int dg   = 8 * w + 2 * a + (q >> 1);           // data granule of this lane's 8B
      int qodd = (q & 1) * 4;                        // ushort offset within granule
      #pragma unroll
      for (int tt = 0; tt < 4; ++tt) {
        int m = 16 * tt + l16;
        f32x4 v = acc[a][tt];
        unsigned int p0 = (unsigned int)f2b(fmaxf(v[0], 0.f)) | ((unsigned int)f2b(fmaxf(v[1], 0.f)) << 16);
        unsigned int p1 = (unsigned int)f2b(fmaxf(v[2], 0.f)) | ((unsigned int)f2b(fmaxf(v[3], 0.f)) << 16);
        int slot = (dg & 16) | ((dg ^ l16) & 15);
        uint2 pp; pp.x = p0; pp.y = p1;
        *(uint2*)(&Xs[buf][m * 256 + slot * 8 + qodd]) = pp;
      }
    }
    // B3: Y writes visible to all waves; still no vmcnt drain.
    asm volatile("s_waitcnt lgkmcnt(0)\n\ts_barrier" ::: "memory");

    // ---- layer 2: wave w -> edges [16w,16w+16), all 32 classes ----
    f32x4 acc2[2];
    acc2[0] = b2init[0]; acc2[1] = b2init[1];
    const int mrow = 16 * w + l16;
    const unsigned short* yrow = &Xs[buf][mrow * 256];
    #pragma unroll
    for (int kk = 0; kk < 8; ++kk) {
      int slot = (4 * kk + q) ^ l16;
      bf16x8 yfrag = *(const bf16x8*)(yrow + slot * 8);
      #pragma unroll
      for (int ct = 0; ct < 2; ++ct) {
        bf16x8 wf = *(const bf16x8*)(&W2l[(16 * ct + l16) * 256 + slot * 8]);
        acc2[ct] = __builtin_amdgcn_mfma_f32_16x16x32_bf16(wf, yfrag, acc2[ct], 0, 0, 0);
      }
    }
    int e = t * MT + mrow;
    if (e < E) {
      #pragma unroll
      for (int ct = 0; ct < 2; ++ct)
        __builtin_nontemporal_store(acc2[ct], (f32x4*)(out + (size_t)e * CLS + 16 * ct + 4 * q));
    }
    // B1': drain the 8 stage glds (oldest); the 2 newest vmem ops are the out
    // stores -> vmcnt(2) skips waiting for their acks.
    asm volatile("s_waitcnt vmcnt(2)\n\ts_barrier" ::: "memory");
    buf ^= 1;
  }
}

// ---------------- fallback v1 (ws fits weights only) --------------------------
__global__ __launch_bounds__(256, 2)
void edge_mlp_v1(const float* __restrict__ emb, const void* __restrict__ eidx,
                 const unsigned short* __restrict__ W1b, const unsigned short* __restrict__ W2b,
                 const float* __restrict__ b1, const float* __restrict__ b2,
                 const int* __restrict__ flag64,
                 float* __restrict__ out, int E, int ntiles) {
  __shared__ unsigned short Xsp[MT * LSTR];
  const int tid  = threadIdx.x;
  const int lane = tid & 63;
  const int w    = tid >> 6;
  const int l16  = lane & 15;
  const int q    = lane >> 4;
  const int is64 = *flag64;

  bf16x8 afr[4][8];
  #pragma unroll
  for (int a = 0; a < 4; ++a) {
    const unsigned short* rp = W1b + (64 * w + 16 * a + l16) * K2 + q * 8;
    #pragma unroll
    for (int kk = 0; kk < 8; ++kk) afr[a][kk] = *(const bf16x8*)(rp + kk * 32);
  }
  f32x4 binit[4];
  #pragma unroll
  for (int a = 0; a < 4; ++a) binit[a] = *(const f32x4*)(b1 + 64 * w + 16 * a + 4 * q);
  f32x4 b2init[2];
  #pragma unroll
  for (int ct = 0; ct < 2; ++ct) b2init[ct] = *(const f32x4*)(b2 + 16 * ct + 4 * q);

  for (int t = blockIdx.x; t < ntiles; t += gridDim.x) {
    const int e0 = t * MT;
    #pragma unroll
    for (int c = 0; c < 8; ++c) {
      int chunk = tid + c * 256;
      int m = chunk >> 5, col8 = chunk & 31;
      int e = e0 + m; if (e >= E) e = E - 1;
      int iofs = (col8 < 16) ? e : (E + e);
      long long node = is64 ? ((const long long*)eidx)[iofs] : (long long)(((const int*)eidx)[iofs]);
      const float* gp = emb + (int)node * D + (col8 & 15) * 8;
      f32x4 lo = *(const f32x4*)gp, hi = *(const f32x4*)(gp + 4);
      ushort8 v;
      v[0] = f2b(lo[0]); v[1] = f2b(lo[1]); v[2] = f2b(lo[2]); v[3] = f2b(lo[3]);
      v[4] = f2b(hi[0]); v[5] = f2b(hi[1]); v[6] = f2b(hi[2]); v[7] = f2b(hi[3]);
      *(ushort8*)&Xsp[m * LSTR + col8 * 8] = v;
    }
    __syncthreads();
    f32x4 acc[4][4];
    #pragma unroll
    for (int a = 0; a < 4; ++a)
      #pragma unroll
      for (int tt = 0; tt < 4; ++tt) acc[a][tt] = binit[a];
    #pragma unroll
    for (int tt = 0; tt < 4; ++tt) {
      #pragma unroll
      for (int kk = 0; kk < 8; ++kk) {
        bf16x8 bfrag = *(const bf16x8*)&Xsp[(16 * tt + l16) * LSTR + kk * 32 + q * 8];
        #pragma unroll
        for (int a = 0; a < 4; ++a)
          acc[a][tt] = __builtin_amdgcn_mfma_f32_16x16x32_bf16(afr[a][kk], bfrag, acc[a][tt], 0, 0, 0);
      }
    }
    __syncthreads();
    #pragma unroll
    for (int a = 0; a < 4; ++a) {
      int n0 = 64 * w + 16 * a + 4 * q;
      #pragma unroll
      for (int tt = 0; tt < 4; ++tt) {
        f32x4 v = acc[a][tt];
        unsigned int p0 = (unsigned int)f2b(fmaxf(v[0], 0.f)) | ((unsigned int)f2b(fmaxf(v[1], 0.f)) << 16);
        unsigned int p1 = (unsigned int)f2b(fmaxf(v[2], 0.f)) | ((unsigned int)f2b(fmaxf(v[3], 0.f)) << 16);
        uint2 pp; pp.x = p0; pp.y = p1;
        *(uint2*)&Xsp[(16 * tt + l16) * LSTR + n0] = pp;
      }
    }
    __syncthreads();
    f32x4 acc2[2];
    acc2[0] = b2init[0]; acc2[1] = b2init[1];
    const int mrow = 16 * w + l16;
    #pragma unroll
    for (int kk = 0; kk < 8; ++kk) {
      bf16x8 yfrag = *(const bf16x8*)&Xsp[mrow * LSTR + kk * 32 + q * 8];
      #pragma unroll
      for (int ct = 0; ct < 2; ++ct) {
        bf16x8 wf = *(const bf16x8*)(W2b + (16 * ct + l16) * H + kk * 32 + q * 8);
        acc2[ct] = __builtin_amdgcn_mfma_f32_16x16x32_bf16(wf, yfrag, acc2[ct], 0, 0, 0);
      }
    }
    int e = e0 + mrow;
    if (e < E) {
      #pragma unroll
      for (int ct = 0; ct < 2; ++ct)
        *(f32x4*)(out + (size_t)e * CLS + 16 * ct + 4 * q) = acc2[ct];
    }
    __syncthreads();
  }
}

// ---------------- last-resort naive ------------------------------------------
__global__ void edge_mlp_naive(const float* __restrict__ emb, const void* __restrict__ eidx,
                               const float* __restrict__ W1, const float* __restrict__ b1,
                               const float* __restrict__ W2, const float* __restrict__ b2,
                               float* __restrict__ out, int E) {
  __shared__ float x[K2];
  __shared__ float y[H];
  __shared__ int flag;
  int e = blockIdx.x;
  if (threadIdx.x == 0) {
    const unsigned int* p = (const unsigned int*)eidx;
    int is64 = 1;
    for (int j = 0; j < 16; ++j) if (p[2 * j + 1] != 0u) { is64 = 0; break; }
    flag = is64;
  }
  __syncthreads();
  int tid = threadIdx.x;
  long long s, d;
  if (flag) { s = ((const long long*)eidx)[e]; d = ((const long long*)eidx)[E + e]; }
  else      { s = ((const int*)eidx)[e];       d = ((const int*)eidx)[E + e]; }
  if (tid < D) { x[tid] = emb[(int)s * D + tid]; x[D + tid] = emb[(int)d * D + tid]; }
  __syncthreads();
  float acc = b1[tid];
  const float* wr = W1 + tid * K2;
  for (int k = 0; k < K2; ++k) acc += x[k] * wr[k];
  y[tid] = fmaxf(acc, 0.f);
  __syncthreads();
  if (tid < CLS) {
    float a2 = b2[tid];
    const float* w2 = W2 + tid * H;
    for (int k = 0; k < H; ++k) a2 += y[k] * w2[k];
    out[(size_t)e * CLS + tid] = a2;
  }
}

extern "C" void kernel_launch(void* const* d_in, const int* in_sizes, int n_in,
                              void* d_out, int out_size, void* d_ws, size_t ws_size,
                              hipStream_t stream) {
  const float* emb  = (const float*)d_in[0];
  const void*  eidx = d_in[1];
  const float* W1   = (const float*)d_in[2];
  const float* b1   = (const float*)d_in[3];
  const float* W2   = (const float*)d_in[4];
  const float* b2   = (const float*)d_in[5];
  float* out = (float*)d_out;
  const int nodes_elems = in_sizes[0];   // N_NODES * D
  const int E = in_sizes[1] / 2;
  const int ntiles = (E + MT - 1) / MT;
  const int n8 = nodes_elems / 8;

  // ws layout: [tab (nodes_elems bf16)][W1b][W2b][W2s][idx32 (2E)][flag]
  size_t off_tab  = 0;
  size_t off_w1   = (off_tab + (size_t)nodes_elems * 2 + 15) & ~(size_t)15;
  size_t off_w2   = off_w1 + (size_t)H * K2 * 2;
  size_t off_w2s  = off_w2 + (size_t)CLS * H * 2;
  size_t off_idx  = (off_w2s + (size_t)CLS * H * 2 + 15) & ~(size_t)15;
  size_t off_flag = off_idx + (size_t)2 * E * 4;
  size_t need_full    = off_flag + 16;
  size_t need_weights = (size_t)(H * K2 + CLS * H) * 2 + 64;

  if (ws_size >= need_full) {
    unsigned short* tab   = (unsigned short*)((char*)d_ws + off_tab);
    unsigned short* W1b   = (unsigned short*)((char*)d_ws + off_w1);
    unsigned short* W2b   = (unsigned short*)((char*)d_ws + off_w2);
    unsigned short* W2s   = (unsigned short*)((char*)d_ws + off_w2s);
    int*            idx32 = (int*)((char*)d_ws + off_idx);

    // grid covers the largest task (node-table granules); all other tasks fit
    // inside the same index range (2E=1M, H*K2=65k, CLS*H=8k <= n8=1.6M).
    int nblk = (n8 + 255) / 256;
    int nblk_idx = (2 * E + 255) / 256;
    if (nblk_idx > nblk) nblk = nblk_idx;
    prep_all<<<nblk, 256, 0, stream>>>(emb, eidx, W1, W2, tab, W1b, W2b, W2s,
                                       idx32, n8, 2 * E);
    // persistent grid: exactly 2 blocks/CU on 256 CUs
    edge_mlp3<<<512, 256, 0, stream>>>(tab, idx32, W1b, W2s, b1, b2, out, E, ntiles);
  } else if (ws_size >= need_weights) {
    unsigned short* W1b = (unsigned short*)d_ws;
    unsigned short* W2b = W1b + H * K2;
    int* flag = (int*)(W2b + CLS * H);
    prep_weights<<<(H * K2 + 255) / 256, 256, 0, stream>>>(W1, W2, eidx, W1b, W2b, flag);
    edge_mlp_v1<<<1024, 256, 0, stream>>>(emb, eidx, W1b, W2b, b1, b2, flag, out, E, ntiles);
  } else {
    edge_mlp_naive<<<E, H, 0, stream>>>(emb, eidx, W1, b1, W2, b2, out, E);
  }
}